// Round 2
// baseline (2491.366 us; speedup 1.0000x reference)
//
#include <hip/hip_runtime.h>

#define N_NODES 50000
#define N_EDGES 800000
#define D_IN 256
#define D_OUT 64
#define NEG_SLOPE 0.01f

#define RPW 8      // rows per wave
#define CHUNK 128  // K-chunk held in registers

// ---------------- Kernel 1: h = X*W + b, and a1/a2 per-node scalars ----------
// One wave per 8 rows; lane = output column. W chunk cached in 128 VGPRs.
__global__ __launch_bounds__(256) void k_gemm(
    const float* __restrict__ feat, const float* __restrict__ Wg,
    const float* __restrict__ bias,
    const float* __restrict__ a1w, const float* __restrict__ a1b,
    const float* __restrict__ a2w, const float* __restrict__ a2b,
    float* __restrict__ h, float* __restrict__ a1, float* __restrict__ a2) {
  int wave = (blockIdx.x * blockDim.x + threadIdx.x) >> 6;
  int lane = threadIdx.x & 63;
  int row0 = wave * RPW;
  if (row0 >= N_NODES) return;

  float acc[RPW];
#pragma unroll
  for (int r = 0; r < RPW; ++r) acc[r] = 0.f;

#pragma unroll
  for (int c = 0; c < D_IN / CHUNK; ++c) {
    const int k0 = c * CHUNK;
    // W chunk -> registers (coalesced 256B per load instr; W is L2-resident)
    float w[CHUNK];
#pragma unroll
    for (int j = 0; j < CHUNK; ++j) w[j] = Wg[(k0 + j) * D_OUT + lane];

#pragma unroll
    for (int r = 0; r < RPW; ++r) {
      const float4* f =
          reinterpret_cast<const float4*>(feat + (size_t)(row0 + r) * D_IN + k0);
      float a = acc[r];
#pragma unroll
      for (int k4 = 0; k4 < CHUNK / 4; ++k4) {
        float4 v = f[k4];
        a = fmaf(v.x, w[4 * k4 + 0], a);
        a = fmaf(v.y, w[4 * k4 + 1], a);
        a = fmaf(v.z, w[4 * k4 + 2], a);
        a = fmaf(v.w, w[4 * k4 + 3], a);
      }
      acc[r] = a;
    }
  }

  float bv = bias[lane];
  float w1 = a1w[lane];
  float w2 = a2w[lane];
  float b1 = a1b[0];
  float b2 = a2b[0];
#pragma unroll
  for (int r = 0; r < RPW; ++r) {
    float hv = acc[r] + bv;
    h[(size_t)(row0 + r) * D_OUT + lane] = hv;
    float s1 = hv * w1;
    float s2 = hv * w2;
#pragma unroll
    for (int off = 32; off > 0; off >>= 1) {
      s1 += __shfl_xor(s1, off);
      s2 += __shfl_xor(s2, off);
    }
    if (lane == 0) {
      a1[row0 + r] = s1 + b1;
      a2[row0 + r] = s2 + b2;
    }
  }
}

// Monotone float->uint encoding so atomicMax(uint) orders like float.
__device__ __forceinline__ unsigned enc_f32(float f) {
  unsigned u = __float_as_uint(f);
  return (u & 0x80000000u) ? ~u : (u | 0x80000000u);
}
__device__ __forceinline__ float dec_f32(unsigned u) {
  return (u & 0x80000000u) ? __uint_as_float(u ^ 0x80000000u)
                           : __uint_as_float(~u);
}

// ---------------- Kernel 2: per-edge score + segment max ----------
__global__ __launch_bounds__(256) void k_score_max(
    const int* __restrict__ rows, const int* __restrict__ cols,
    const float* __restrict__ a1, const float* __restrict__ a2,
    unsigned* __restrict__ rmax) {
  int e = blockIdx.x * blockDim.x + threadIdx.x;
  if (e >= N_EDGES) return;
  int r = rows[e], c = cols[e];
  float s = a1[r] + a2[c];
  s = (s > 0.f) ? s : NEG_SLOPE * s;
  atomicMax(&rmax[r], enc_f32(s));
}

// ---------------- Kernel 3: ex = exp(score - rowmax), segment sum ----------
__global__ __launch_bounds__(256) void k_exp_sum(
    const int* __restrict__ rows, const int* __restrict__ cols,
    const float* __restrict__ a1, const float* __restrict__ a2,
    const unsigned* __restrict__ rmax,
    float* __restrict__ ex, float* __restrict__ denom) {
  int e = blockIdx.x * blockDim.x + threadIdx.x;
  if (e >= N_EDGES) return;
  int r = rows[e], c = cols[e];
  float s = a1[r] + a2[c];
  s = (s > 0.f) ? s : NEG_SLOPE * s;
  float m = dec_f32(rmax[r]);
  float v = __expf(s - m);
  ex[e] = v;
  atomicAdd(&denom[r], v);
}

// ---------------- Kernel 4: out[r] += (ex/denom[r]) * h[c] ----------
// One wave per edge, lane = output dim. Coalesced h read and out atomics.
__global__ __launch_bounds__(256) void k_aggregate(
    const int* __restrict__ rows, const int* __restrict__ cols,
    const float* __restrict__ ex, const float* __restrict__ denom,
    const float* __restrict__ h, float* __restrict__ out) {
  long long gt = (long long)blockIdx.x * blockDim.x + threadIdx.x;
  int e = (int)(gt >> 6);
  int lane = (int)(gt & 63);
  if (e >= N_EDGES) return;
  int r = rows[e], c = cols[e];
  float att = ex[e] / denom[r];
  atomicAdd(&out[(size_t)r * D_OUT + lane], att * h[(size_t)c * D_OUT + lane]);
}

extern "C" void kernel_launch(void* const* d_in, const int* in_sizes, int n_in,
                              void* d_out, int out_size, void* d_ws, size_t ws_size,
                              hipStream_t stream) {
  const float* feat = (const float*)d_in[0];
  const int* eidx   = (const int*)d_in[1];   // [2, E] int32 (JAX x64 disabled)
  // d_in[2] edge_values: unused by reference output
  const float* W    = (const float*)d_in[3];
  const float* bias = (const float*)d_in[4];
  const float* a1w  = (const float*)d_in[5];
  const float* a1b  = (const float*)d_in[6];
  const float* a2w  = (const float*)d_in[7];
  const float* a2b  = (const float*)d_in[8];
  // a3_w, a3_b unused
  float* out = (float*)d_out;

  const int* rows = eidx;
  const int* cols = eidx + N_EDGES;

  // workspace layout
  char* ws = (char*)d_ws;
  float*    h     = (float*)ws;                       // N*64 f32 = 12.8 MB
  float*    a1    = (float*)(ws + 12800000);          // 200 KB
  float*    a2    = (float*)(ws + 13000000);          // 200 KB
  unsigned* rmax  = (unsigned*)(ws + 13200000);       // 200 KB
  float*    denom = (float*)(ws + 13400000);          // 200 KB
  float*    ex    = (float*)(ws + 13600000);          // 3.2 MB -> total 16.8 MB

  // init: rmax=0 encodes "below -inf"; denom=0; out=0
  hipMemsetAsync(rmax, 0, N_NODES * sizeof(unsigned), stream);
  hipMemsetAsync(denom, 0, N_NODES * sizeof(float), stream);
  hipMemsetAsync(out, 0, (size_t)N_NODES * D_OUT * sizeof(float), stream);

  {
    // 50000 rows / 8 per wave = 6250 waves; 4 waves per block -> 1563 blocks
    int waves = (N_NODES + RPW - 1) / RPW;
    int blocks = (waves + 3) / 4;
    k_gemm<<<blocks, 256, 0, stream>>>(feat, W, bias, a1w, a1b, a2w, a2b, h, a1, a2);
  }
  {
    int blocks = (N_EDGES + 255) / 256;
    k_score_max<<<blocks, 256, 0, stream>>>(rows, cols, a1, a2, rmax);
    k_exp_sum<<<blocks, 256, 0, stream>>>(rows, cols, a1, a2, rmax, ex, denom);
  }
  {
    long long threads = (long long)N_EDGES * 64;
    int blocks = (int)((threads + 255) / 256);
    k_aggregate<<<blocks, 256, 0, stream>>>(rows, cols, ex, denom, h, out);
  }
}

// Round 3
// 397.996 us; speedup vs baseline: 6.2598x; 6.2598x over previous
//
#include <hip/hip_runtime.h>

#define N_NODES 50000
#define N_EDGES 800000
#define D_IN 256
#define D_OUT 64
#define NEG_SLOPE 0.01f

#define RPW 8     // rows per wave
#define CHUNK 32  // K-chunk held in registers (32 regs — no spill; 128 spilled)

// ---------------- Kernel 1: h = X*W + b, and a1/a2 per-node scalars ----------
// One wave per 8 rows; lane = output column. W chunk cached in 32 VGPRs,
// reused across 8 rows -> W L2 traffic = 50000/8 * 64KB = 400 MB.
__global__ __launch_bounds__(256) void k_gemm(
    const float* __restrict__ feat, const float* __restrict__ Wg,
    const float* __restrict__ bias,
    const float* __restrict__ a1w, const float* __restrict__ a1b,
    const float* __restrict__ a2w, const float* __restrict__ a2b,
    float* __restrict__ h, float* __restrict__ a1, float* __restrict__ a2) {
  int wave = (blockIdx.x * blockDim.x + threadIdx.x) >> 6;
  int lane = threadIdx.x & 63;
  int row0 = wave * RPW;
  if (row0 >= N_NODES) return;

  float acc[RPW];
#pragma unroll
  for (int r = 0; r < RPW; ++r) acc[r] = 0.f;

  for (int c = 0; c < D_IN / CHUNK; ++c) {
    const int k0 = c * CHUNK;
    // W chunk -> registers (coalesced 256B per load instr; W is L2-resident)
    float w[CHUNK];
#pragma unroll
    for (int j = 0; j < CHUNK; ++j) w[j] = Wg[(k0 + j) * D_OUT + lane];

#pragma unroll
    for (int r = 0; r < RPW; ++r) {
      const float4* f =
          reinterpret_cast<const float4*>(feat + (size_t)(row0 + r) * D_IN + k0);
      float a = acc[r];
#pragma unroll
      for (int k4 = 0; k4 < CHUNK / 4; ++k4) {
        float4 v = f[k4];
        a = fmaf(v.x, w[4 * k4 + 0], a);
        a = fmaf(v.y, w[4 * k4 + 1], a);
        a = fmaf(v.z, w[4 * k4 + 2], a);
        a = fmaf(v.w, w[4 * k4 + 3], a);
      }
      acc[r] = a;
    }
  }

  float bv = bias[lane];
  float w1 = a1w[lane];
  float w2 = a2w[lane];
  float b1 = a1b[0];
  float b2 = a2b[0];
#pragma unroll
  for (int r = 0; r < RPW; ++r) {
    float hv = acc[r] + bv;
    h[(size_t)(row0 + r) * D_OUT + lane] = hv;
    float s1 = hv * w1;
    float s2 = hv * w2;
#pragma unroll
    for (int off = 32; off > 0; off >>= 1) {
      s1 += __shfl_xor(s1, off);
      s2 += __shfl_xor(s2, off);
    }
    if (lane == 0) {
      a1[row0 + r] = s1 + b1;
      a2[row0 + r] = s2 + b2;
    }
  }
}

// Monotone float->uint encoding so atomicMax(uint) orders like float.
__device__ __forceinline__ unsigned enc_f32(float f) {
  unsigned u = __float_as_uint(f);
  return (u & 0x80000000u) ? ~u : (u | 0x80000000u);
}
__device__ __forceinline__ float dec_f32(unsigned u) {
  return (u & 0x80000000u) ? __uint_as_float(u ^ 0x80000000u)
                           : __uint_as_float(~u);
}

// ---------------- Kernel 2: per-edge score + segment max ----------
__global__ __launch_bounds__(256) void k_score_max(
    const int* __restrict__ rows, const int* __restrict__ cols,
    const float* __restrict__ a1, const float* __restrict__ a2,
    unsigned* __restrict__ rmax) {
  int e = blockIdx.x * blockDim.x + threadIdx.x;
  if (e >= N_EDGES) return;
  int r = rows[e], c = cols[e];
  float s = a1[r] + a2[c];
  s = (s > 0.f) ? s : NEG_SLOPE * s;
  atomicMax(&rmax[r], enc_f32(s));
}

// ---------------- Kernel 3: ex = exp(score - rowmax), segment sum ----------
__global__ __launch_bounds__(256) void k_exp_sum(
    const int* __restrict__ rows, const int* __restrict__ cols,
    const float* __restrict__ a1, const float* __restrict__ a2,
    const unsigned* __restrict__ rmax,
    float* __restrict__ ex, float* __restrict__ denom) {
  int e = blockIdx.x * blockDim.x + threadIdx.x;
  if (e >= N_EDGES) return;
  int r = rows[e], c = cols[e];
  float s = a1[r] + a2[c];
  s = (s > 0.f) ? s : NEG_SLOPE * s;
  float m = dec_f32(rmax[r]);
  float v = __expf(s - m);
  ex[e] = v;
  atomicAdd(&denom[r], v);
}

// ---------------- Kernel 4: out[r] += (ex/denom[r]) * h[c] ----------
// One wave per edge, lane = output dim. Coalesced h read and out atomics.
__global__ __launch_bounds__(256) void k_aggregate(
    const int* __restrict__ rows, const int* __restrict__ cols,
    const float* __restrict__ ex, const float* __restrict__ denom,
    const float* __restrict__ h, float* __restrict__ out) {
  long long gt = (long long)blockIdx.x * blockDim.x + threadIdx.x;
  int e = (int)(gt >> 6);
  int lane = (int)(gt & 63);
  if (e >= N_EDGES) return;
  int r = rows[e], c = cols[e];
  float att = ex[e] / denom[r];
  atomicAdd(&out[(size_t)r * D_OUT + lane], att * h[(size_t)c * D_OUT + lane]);
}

extern "C" void kernel_launch(void* const* d_in, const int* in_sizes, int n_in,
                              void* d_out, int out_size, void* d_ws, size_t ws_size,
                              hipStream_t stream) {
  const float* feat = (const float*)d_in[0];
  const int* eidx   = (const int*)d_in[1];   // [2, E] int32 (JAX x64 disabled)
  // d_in[2] edge_values: unused by reference output
  const float* W    = (const float*)d_in[3];
  const float* bias = (const float*)d_in[4];
  const float* a1w  = (const float*)d_in[5];
  const float* a1b  = (const float*)d_in[6];
  const float* a2w  = (const float*)d_in[7];
  const float* a2b  = (const float*)d_in[8];
  // a3_w, a3_b unused
  float* out = (float*)d_out;

  const int* rows = eidx;
  const int* cols = eidx + N_EDGES;

  // workspace layout
  char* ws = (char*)d_ws;
  float*    h     = (float*)ws;                       // N*64 f32 = 12.8 MB
  float*    a1    = (float*)(ws + 12800000);          // 200 KB
  float*    a2    = (float*)(ws + 13000000);          // 200 KB
  unsigned* rmax  = (unsigned*)(ws + 13200000);       // 200 KB
  float*    denom = (float*)(ws + 13400000);          // 200 KB
  float*    ex    = (float*)(ws + 13600000);          // 3.2 MB -> total 16.8 MB

  // init: rmax=0 encodes "below -inf"; denom=0; out=0
  hipMemsetAsync(rmax, 0, N_NODES * sizeof(unsigned), stream);
  hipMemsetAsync(denom, 0, N_NODES * sizeof(float), stream);
  hipMemsetAsync(out, 0, (size_t)N_NODES * D_OUT * sizeof(float), stream);

  {
    // 50000 rows / 8 per wave = 6250 waves; 4 waves per block -> 1563 blocks
    int waves = (N_NODES + RPW - 1) / RPW;
    int blocks = (waves + 3) / 4;
    k_gemm<<<blocks, 256, 0, stream>>>(feat, W, bias, a1w, a1b, a2w, a2b, h, a1, a2);
  }
  {
    int blocks = (N_EDGES + 255) / 256;
    k_score_max<<<blocks, 256, 0, stream>>>(rows, cols, a1, a2, rmax);
    k_exp_sum<<<blocks, 256, 0, stream>>>(rows, cols, a1, a2, rmax, ex, denom);
  }
  {
    long long threads = (long long)N_EDGES * 64;
    int blocks = (int)((threads + 255) / 256);
    k_aggregate<<<blocks, 256, 0, stream>>>(rows, cols, ex, denom, h, out);
  }
}

// Round 4
// 307.730 us; speedup vs baseline: 8.0959x; 1.2933x over previous
//
#include <hip/hip_runtime.h>

#define N_NODES 50000
#define N_EDGES 800000
#define D_IN 256
#define D_OUT 64
#define NEG_SLOPE 0.01f

#define RPW 8     // rows per wave (gemm)
#define CHUNK 32  // K-chunk held in registers (32 regs — no spill; 128 spilled)

// ---------------- Kernel 1: h = X*W + b, and a1/a2 per-node scalars ----------
__global__ __launch_bounds__(256) void k_gemm(
    const float* __restrict__ feat, const float* __restrict__ Wg,
    const float* __restrict__ bias,
    const float* __restrict__ a1w, const float* __restrict__ a1b,
    const float* __restrict__ a2w, const float* __restrict__ a2b,
    float* __restrict__ h, float* __restrict__ a1, float* __restrict__ a2) {
  int wave = (blockIdx.x * blockDim.x + threadIdx.x) >> 6;
  int lane = threadIdx.x & 63;
  int row0 = wave * RPW;
  if (row0 >= N_NODES) return;

  float acc[RPW];
#pragma unroll
  for (int r = 0; r < RPW; ++r) acc[r] = 0.f;

  for (int c = 0; c < D_IN / CHUNK; ++c) {
    const int k0 = c * CHUNK;
    float w[CHUNK];
#pragma unroll
    for (int j = 0; j < CHUNK; ++j) w[j] = Wg[(k0 + j) * D_OUT + lane];

#pragma unroll
    for (int r = 0; r < RPW; ++r) {
      const float4* f =
          reinterpret_cast<const float4*>(feat + (size_t)(row0 + r) * D_IN + k0);
      float a = acc[r];
#pragma unroll
      for (int k4 = 0; k4 < CHUNK / 4; ++k4) {
        float4 v = f[k4];
        a = fmaf(v.x, w[4 * k4 + 0], a);
        a = fmaf(v.y, w[4 * k4 + 1], a);
        a = fmaf(v.z, w[4 * k4 + 2], a);
        a = fmaf(v.w, w[4 * k4 + 3], a);
      }
      acc[r] = a;
    }
  }

  float bv = bias[lane];
  float w1 = a1w[lane];
  float w2 = a2w[lane];
  float b1 = a1b[0];
  float b2 = a2b[0];
#pragma unroll
  for (int r = 0; r < RPW; ++r) {
    float hv = acc[r] + bv;
    h[(size_t)(row0 + r) * D_OUT + lane] = hv;
    float s1 = hv * w1;
    float s2 = hv * w2;
#pragma unroll
    for (int off = 32; off > 0; off >>= 1) {
      s1 += __shfl_xor(s1, off);
      s2 += __shfl_xor(s2, off);
    }
    if (lane == 0) {
      a1[row0 + r] = s1 + b1;
      a2[row0 + r] = s2 + b2;
    }
  }
}

// ---------------- Kernel 2: per-row edge histogram ----------
__global__ __launch_bounds__(256) void k_count(
    const int* __restrict__ rows, unsigned* __restrict__ counts) {
  int e = blockIdx.x * blockDim.x + threadIdx.x;
  if (e >= N_EDGES) return;
  atomicAdd(&counts[rows[e]], 1u);
}

// ---------------- Scan: counts -> exclusive prefix (start[]) ----------
// Pass 1: per-block (256-wide) exclusive scan, block totals to bsum.
__global__ __launch_bounds__(256) void k_scan_blocks(
    const unsigned* __restrict__ counts, unsigned* __restrict__ partial,
    unsigned* __restrict__ bsum) {
  int i = blockIdx.x * 256 + threadIdx.x;
  int lane = threadIdx.x & 63, wid = threadIdx.x >> 6;
  unsigned v = (i < N_NODES) ? counts[i] : 0u;
  unsigned x = v;
#pragma unroll
  for (int off = 1; off < 64; off <<= 1) {
    unsigned y = __shfl_up(x, off);
    if (lane >= off) x += y;
  }
  __shared__ unsigned wtot[4];
  if (lane == 63) wtot[wid] = x;
  __syncthreads();
  unsigned wo = 0;
  for (int wq = 0; wq < wid; ++wq) wo += wtot[wq];
  unsigned incl = x + wo;
  if (i < N_NODES) partial[i] = incl - v;
  if (threadIdx.x == 255) bsum[blockIdx.x] = incl;
}

// Pass 2: exclusive scan of the block totals (<=256 of them), in place.
__global__ __launch_bounds__(256) void k_scan_bsums(
    unsigned* __restrict__ bsum, int nblocks) {
  int i = threadIdx.x;
  int lane = i & 63, wid = i >> 6;
  unsigned v = (i < nblocks) ? bsum[i] : 0u;
  unsigned x = v;
#pragma unroll
  for (int off = 1; off < 64; off <<= 1) {
    unsigned y = __shfl_up(x, off);
    if (lane >= off) x += y;
  }
  __shared__ unsigned wtot[4];
  if (lane == 63) wtot[wid] = x;
  __syncthreads();
  unsigned wo = 0;
  for (int wq = 0; wq < wid; ++wq) wo += wtot[wq];
  if (i < nblocks) bsum[i] = (x + wo) - v;
}

// Pass 3: add block offsets; init cursor; write start[N] = E.
__global__ __launch_bounds__(256) void k_scan_add(
    unsigned* __restrict__ start, const unsigned* __restrict__ bsum,
    unsigned* __restrict__ cursor) {
  int i = blockIdx.x * 256 + threadIdx.x;
  if (i < N_NODES) {
    unsigned s = start[i] + bsum[i >> 8];
    start[i] = s;
    cursor[i] = s;
  } else if (i == N_NODES) {
    start[N_NODES] = N_EDGES;
  }
}

// ---------------- Kernel 3: scatter edges into CSR order ----------
__global__ __launch_bounds__(256) void k_scatter(
    const int* __restrict__ rows, const int* __restrict__ cols,
    const float* __restrict__ a1, const float* __restrict__ a2,
    unsigned* __restrict__ cursor, int2* __restrict__ es) {
  int e = blockIdx.x * blockDim.x + threadIdx.x;
  if (e >= N_EDGES) return;
  int r = rows[e], c = cols[e];
  float s = a1[r] + a2[c];
  s = (s > 0.f) ? s : NEG_SLOPE * s;
  unsigned pos = atomicAdd(&cursor[r], 1u);
  es[pos] = make_int2(c, __float_as_int(s));
}

// ---------------- Kernel 4: per-row softmax + aggregate, atomic-free --------
// One wave per row, lane = output dim. h reads coalesced 256B/edge;
// out written exactly once.
__global__ __launch_bounds__(256) void k_row_agg(
    const unsigned* __restrict__ start, const int2* __restrict__ es,
    const float* __restrict__ h, float* __restrict__ out) {
  int gt = blockIdx.x * blockDim.x + threadIdx.x;
  int r = gt >> 6;
  int lane = gt & 63;
  if (r >= N_NODES) return;
  int beg = (int)start[r], end = (int)start[r + 1];

  float m = -1e30f;
  for (int i = beg; i < end; ++i) m = fmaxf(m, __int_as_float(es[i].y));

  float d = 0.f, acc = 0.f;
  for (int i = beg; i < end; ++i) {
    int2 e = es[i];
    float v = __expf(__int_as_float(e.y) - m);
    d += v;
    acc = fmaf(v, h[(size_t)e.x * D_OUT + lane], acc);
  }
  out[(size_t)r * D_OUT + lane] = (end > beg) ? acc / d : 0.f;
}

extern "C" void kernel_launch(void* const* d_in, const int* in_sizes, int n_in,
                              void* d_out, int out_size, void* d_ws, size_t ws_size,
                              hipStream_t stream) {
  const float* feat = (const float*)d_in[0];
  const int* eidx   = (const int*)d_in[1];   // [2, E] int32 (JAX x64 disabled)
  const float* W    = (const float*)d_in[3];
  const float* bias = (const float*)d_in[4];
  const float* a1w  = (const float*)d_in[5];
  const float* a1b  = (const float*)d_in[6];
  const float* a2w  = (const float*)d_in[7];
  const float* a2b  = (const float*)d_in[8];
  float* out = (float*)d_out;

  const int* rows = eidx;
  const int* cols = eidx + N_EDGES;

  // workspace layout (~20.3 MB)
  char* ws = (char*)d_ws;
  float*    h      = (float*)ws;                      // 12.8 MB
  int2*     es     = (int2*)(ws + 12800000);          // 6.4 MB
  float*    a1     = (float*)(ws + 19200000);         // 200 KB
  float*    a2     = (float*)(ws + 19400000);         // 200 KB
  unsigned* counts = (unsigned*)(ws + 19600000);      // 200 KB
  unsigned* start  = (unsigned*)(ws + 19800000);      // 200 KB (+4)
  unsigned* cursor = (unsigned*)(ws + 20000064);      // 200 KB
  unsigned* bsum   = (unsigned*)(ws + 20200064);      // 1 KB

  hipMemsetAsync(counts, 0, N_NODES * sizeof(unsigned), stream);

  const int SCAN_BLOCKS = (N_NODES + 255) / 256;  // 196

  {
    int waves = (N_NODES + RPW - 1) / RPW;
    int blocks = (waves + 3) / 4;
    k_gemm<<<blocks, 256, 0, stream>>>(feat, W, bias, a1w, a1b, a2w, a2b, h, a1, a2);
  }
  {
    int blocks = (N_EDGES + 255) / 256;
    k_count<<<blocks, 256, 0, stream>>>(rows, counts);
  }
  k_scan_blocks<<<SCAN_BLOCKS, 256, 0, stream>>>(counts, start, bsum);
  k_scan_bsums<<<1, 256, 0, stream>>>(bsum, SCAN_BLOCKS);
  k_scan_add<<<(N_NODES + 256) / 256, 256, 0, stream>>>(start, bsum, cursor);
  {
    int blocks = (N_EDGES + 255) / 256;
    k_scatter<<<blocks, 256, 0, stream>>>(rows, cols, a1, a2, cursor, es);
  }
  {
    long long threads = (long long)N_NODES * 64;
    int blocks = (int)((threads + 255) / 256);
    k_row_agg<<<blocks, 256, 0, stream>>>(start, es, h, out);
  }
}

// Round 5
// 209.205 us; speedup vs baseline: 11.9087x; 1.4709x over previous
//
#include <hip/hip_runtime.h>

#define N_NODES 50000
#define N_EDGES 800000
#define D_IN 256
#define D_OUT 64
#define NEG_SLOPE 0.01f

typedef unsigned short ushort;
typedef short short8 __attribute__((ext_vector_type(8)));
typedef float f32x4 __attribute__((ext_vector_type(4)));

// Split f32 into hi/lo bf16 (truncation): a ≈ hi + lo, |err| ~ 2^-16 rel.
__device__ __forceinline__ void split2(float a, ushort& hi, ushort& lo) {
  unsigned ub = __float_as_uint(a);
  hi = (ushort)(ub >> 16);
  float hf = __uint_as_float(ub & 0xFFFF0000u);
  lo = (ushort)(__float_as_uint(a - hf) >> 16);
}

// ---------------- Kernel 0: pre-split W into MFMA B-fragment order ----------
// Bfrag layout: [(ks*4+ct)*64 + lane] -> ushort8 (j=0..7), where the fragment
// element is W[ks*32 + (lane>>4)*8 + j][ct*16 + (lane&15)].
__global__ __launch_bounds__(256) void k_wsplit(
    const float* __restrict__ W, short8* __restrict__ Bh,
    short8* __restrict__ Bl) {
  int t = blockIdx.x * 256 + threadIdx.x;  // 2048 threads total
  if (t >= 8 * 4 * 64) return;
  int lane = t & 63;
  int ct = (t >> 6) & 3;
  int ks = t >> 8;
  int k0 = ks * 32 + (lane >> 4) * 8;
  int col = ct * 16 + (lane & 15);
  short8 h8, l8;
#pragma unroll
  for (int j = 0; j < 8; ++j) {
    ushort hi, lo;
    split2(W[(size_t)(k0 + j) * D_OUT + col], hi, lo);
    h8[j] = (short)hi;
    l8[j] = (short)lo;
  }
  Bh[t] = h8;
  Bl[t] = l8;
}

// ---------------- Kernel 1: h = X*W + b via bf16 MFMA (hi/lo split) --------
// One wave per 16 rows. A-fragments loaded straight from global per lane;
// B-fragments from the pre-swizzled Bh/Bl (coalesced 16B/lane).
__global__ __launch_bounds__(256) void k_gemm_mfma(
    const float* __restrict__ feat, const short8* __restrict__ Bh,
    const short8* __restrict__ Bl, const float* __restrict__ bias,
    const float* __restrict__ a1w, const float* __restrict__ a1b,
    const float* __restrict__ a2w, const float* __restrict__ a2b,
    float* __restrict__ h, float* __restrict__ a1, float* __restrict__ a2) {
  int wid = (blockIdx.x * 256 + threadIdx.x) >> 6;
  int lane = threadIdx.x & 63;
  if (wid >= N_NODES / 16) return;  // 3125 waves exactly
  int row0 = wid * 16;

  int arow = row0 + (lane & 15);
  const float* fp = feat + (size_t)arow * D_IN + ((lane >> 4) * 8);

  f32x4 acc[4];
#pragma unroll
  for (int ct = 0; ct < 4; ++ct) acc[ct] = (f32x4){0.f, 0.f, 0.f, 0.f};

#pragma unroll
  for (int ks = 0; ks < 8; ++ks) {
    float4 v0 = *reinterpret_cast<const float4*>(fp + ks * 32);
    float4 v1 = *reinterpret_cast<const float4*>(fp + ks * 32 + 4);
    float av[8] = {v0.x, v0.y, v0.z, v0.w, v1.x, v1.y, v1.z, v1.w};
    short8 ah, al;
#pragma unroll
    for (int j = 0; j < 8; ++j) {
      ushort hi, lo;
      split2(av[j], hi, lo);
      ah[j] = (short)hi;
      al[j] = (short)lo;
    }
#pragma unroll
    for (int ct = 0; ct < 4; ++ct) {
      short8 bh = Bh[(ks * 4 + ct) * 64 + lane];
      short8 bl = Bl[(ks * 4 + ct) * 64 + lane];
      acc[ct] = __builtin_amdgcn_mfma_f32_16x16x32_bf16(ah, bh, acc[ct], 0, 0, 0);
      acc[ct] = __builtin_amdgcn_mfma_f32_16x16x32_bf16(ah, bl, acc[ct], 0, 0, 0);
      acc[ct] = __builtin_amdgcn_mfma_f32_16x16x32_bf16(al, bh, acc[ct], 0, 0, 0);
    }
  }

  // Epilogue. C layout: col = lane&15 (within ct*16..), row = (lane>>4)*4 + r.
  int lo16 = lane & 15;
  int hi4 = (lane >> 4) * 4;
  float bv[4], w1[4], w2[4];
#pragma unroll
  for (int ct = 0; ct < 4; ++ct) {
    bv[ct] = bias[ct * 16 + lo16];
    w1[ct] = a1w[ct * 16 + lo16];
    w2[ct] = a2w[ct * 16 + lo16];
  }
  float b1 = a1b[0], b2 = a2b[0];

#pragma unroll
  for (int r = 0; r < 4; ++r) {
    int row = row0 + hi4 + r;
    float s1 = 0.f, s2 = 0.f;
#pragma unroll
    for (int ct = 0; ct < 4; ++ct) {
      float hv = acc[ct][r] + bv[ct];
      h[(size_t)row * D_OUT + ct * 16 + lo16] = hv;
      s1 = fmaf(hv, w1[ct], s1);
      s2 = fmaf(hv, w2[ct], s2);
    }
#pragma unroll
    for (int off = 1; off < 16; off <<= 1) {
      s1 += __shfl_xor(s1, off);
      s2 += __shfl_xor(s2, off);
    }
    if (lo16 == 0) {
      a1[row] = s1 + b1;
      a2[row] = s2 + b2;
    }
  }
}

// ---------------- Kernel 2: per-row edge histogram ----------
__global__ __launch_bounds__(256) void k_count(
    const int* __restrict__ rows, unsigned* __restrict__ counts) {
  int e = blockIdx.x * blockDim.x + threadIdx.x;
  if (e >= N_EDGES) return;
  atomicAdd(&counts[rows[e]], 1u);
}

// ---------------- Scan: counts -> exclusive prefix (start[]) ----------
__global__ __launch_bounds__(256) void k_scan_blocks(
    const unsigned* __restrict__ counts, unsigned* __restrict__ partial,
    unsigned* __restrict__ bsum) {
  int i = blockIdx.x * 256 + threadIdx.x;
  int lane = threadIdx.x & 63, wid = threadIdx.x >> 6;
  unsigned v = (i < N_NODES) ? counts[i] : 0u;
  unsigned x = v;
#pragma unroll
  for (int off = 1; off < 64; off <<= 1) {
    unsigned y = __shfl_up(x, off);
    if (lane >= off) x += y;
  }
  __shared__ unsigned wtot[4];
  if (lane == 63) wtot[wid] = x;
  __syncthreads();
  unsigned wo = 0;
  for (int wq = 0; wq < wid; ++wq) wo += wtot[wq];
  unsigned incl = x + wo;
  if (i < N_NODES) partial[i] = incl - v;
  if (threadIdx.x == 255) bsum[blockIdx.x] = incl;
}

__global__ __launch_bounds__(256) void k_scan_bsums(
    unsigned* __restrict__ bsum, int nblocks) {
  int i = threadIdx.x;
  int lane = i & 63, wid = i >> 6;
  unsigned v = (i < nblocks) ? bsum[i] : 0u;
  unsigned x = v;
#pragma unroll
  for (int off = 1; off < 64; off <<= 1) {
    unsigned y = __shfl_up(x, off);
    if (lane >= off) x += y;
  }
  __shared__ unsigned wtot[4];
  if (lane == 63) wtot[wid] = x;
  __syncthreads();
  unsigned wo = 0;
  for (int wq = 0; wq < wid; ++wq) wo += wtot[wq];
  if (i < nblocks) bsum[i] = (x + wo) - v;
}

__global__ __launch_bounds__(256) void k_scan_add(
    unsigned* __restrict__ start, const unsigned* __restrict__ bsum,
    unsigned* __restrict__ cursor) {
  int i = blockIdx.x * 256 + threadIdx.x;
  if (i < N_NODES) {
    unsigned s = start[i] + bsum[i >> 8];
    start[i] = s;
    cursor[i] = s;
  } else if (i == N_NODES) {
    start[N_NODES] = N_EDGES;
  }
}

// ---------------- Kernel 3: scatter edges into CSR order ----------
__global__ __launch_bounds__(256) void k_scatter(
    const int* __restrict__ rows, const int* __restrict__ cols,
    const float* __restrict__ a1, const float* __restrict__ a2,
    unsigned* __restrict__ cursor, int2* __restrict__ es) {
  int e = blockIdx.x * blockDim.x + threadIdx.x;
  if (e >= N_EDGES) return;
  int r = rows[e], c = cols[e];
  float s = a1[r] + a2[c];
  s = (s > 0.f) ? s : NEG_SLOPE * s;
  unsigned pos = atomicAdd(&cursor[r], 1u);
  es[pos] = make_int2(c, __float_as_int(s));
}

// ---------------- Kernel 4: per-row softmax + aggregate, atomic-free --------
__global__ __launch_bounds__(256) void k_row_agg(
    const unsigned* __restrict__ start, const int2* __restrict__ es,
    const float* __restrict__ h, float* __restrict__ out) {
  int gt = blockIdx.x * blockDim.x + threadIdx.x;
  int r = gt >> 6;
  int lane = gt & 63;
  if (r >= N_NODES) return;
  int beg = (int)start[r], end = (int)start[r + 1];

  float m = -1e30f;
  for (int i = beg; i < end; ++i) m = fmaxf(m, __int_as_float(es[i].y));

  float d = 0.f, acc = 0.f;
  for (int i = beg; i < end; ++i) {
    int2 e = es[i];
    float v = __expf(__int_as_float(e.y) - m);
    d += v;
    acc = fmaf(v, h[(size_t)e.x * D_OUT + lane], acc);
  }
  out[(size_t)r * D_OUT + lane] = (end > beg) ? acc / d : 0.f;
}

extern "C" void kernel_launch(void* const* d_in, const int* in_sizes, int n_in,
                              void* d_out, int out_size, void* d_ws, size_t ws_size,
                              hipStream_t stream) {
  const float* feat = (const float*)d_in[0];
  const int* eidx   = (const int*)d_in[1];   // [2, E] int32 (JAX x64 disabled)
  const float* W    = (const float*)d_in[3];
  const float* bias = (const float*)d_in[4];
  const float* a1w  = (const float*)d_in[5];
  const float* a1b  = (const float*)d_in[6];
  const float* a2w  = (const float*)d_in[7];
  const float* a2b  = (const float*)d_in[8];
  float* out = (float*)d_out;

  const int* rows = eidx;
  const int* cols = eidx + N_EDGES;

  // workspace layout (~20.4 MB)
  char* ws = (char*)d_ws;
  float*    h      = (float*)ws;                      // 12.8 MB
  int2*     es     = (int2*)(ws + 12800000);          // 6.4 MB
  float*    a1     = (float*)(ws + 19200000);         // 200 KB
  float*    a2     = (float*)(ws + 19400000);         // 200 KB
  unsigned* counts = (unsigned*)(ws + 19600000);      // 200 KB
  unsigned* start  = (unsigned*)(ws + 19800000);      // 200 KB (+4)
  unsigned* cursor = (unsigned*)(ws + 20000064);      // 200 KB
  unsigned* bsum   = (unsigned*)(ws + 20200064);      // 1 KB
  short8*   Bh     = (short8*)(ws + 20201088);        // 32 KB
  short8*   Bl     = (short8*)(ws + 20233856);        // 32 KB

  hipMemsetAsync(counts, 0, N_NODES * sizeof(unsigned), stream);

  const int SCAN_BLOCKS = (N_NODES + 255) / 256;  // 196

  k_wsplit<<<8, 256, 0, stream>>>(W, Bh, Bl);
  {
    int waves = N_NODES / 16;  // 3125
    int blocks = (waves + 3) / 4;
    k_gemm_mfma<<<blocks, 256, 0, stream>>>(feat, Bh, Bl, bias, a1w, a1b, a2w,
                                            a2b, h, a1, a2);
  }
  {
    int blocks = (N_EDGES + 255) / 256;
    k_count<<<blocks, 256, 0, stream>>>(rows, counts);
  }
  k_scan_blocks<<<SCAN_BLOCKS, 256, 0, stream>>>(counts, start, bsum);
  k_scan_bsums<<<1, 256, 0, stream>>>(bsum, SCAN_BLOCKS);
  k_scan_add<<<(N_NODES + 256) / 256, 256, 0, stream>>>(start, bsum, cursor);
  {
    int blocks = (N_EDGES + 255) / 256;
    k_scatter<<<blocks, 256, 0, stream>>>(rows, cols, a1, a2, cursor, es);
  }
  {
    long long threads = (long long)N_NODES * 64;
    int blocks = (int)((threads + 255) / 256);
    k_row_agg<<<blocks, 256, 0, stream>>>(start, es, h, out);
  }
}

// Round 6
// 159.664 us; speedup vs baseline: 15.6038x; 1.3103x over previous
//
#include <hip/hip_runtime.h>

#define N_NODES 50000
#define N_EDGES 800000
#define D_IN 256
#define D_OUT 64
#define NEG_SLOPE 0.01f

typedef unsigned short ushort;
typedef short short8 __attribute__((ext_vector_type(8)));
typedef float f32x4 __attribute__((ext_vector_type(4)));

// Split f32 into hi/lo bf16 (truncation): a ≈ hi + lo, |err| ~ 2^-16 rel.
__device__ __forceinline__ void split2(float a, ushort& hi, ushort& lo) {
  unsigned ub = __float_as_uint(a);
  hi = (ushort)(ub >> 16);
  float hf = __uint_as_float(ub & 0xFFFF0000u);
  lo = (ushort)(__float_as_uint(a - hf) >> 16);
}

// ---------------- Kernel 0: pre-split W into MFMA B-fragment order ----------
__global__ __launch_bounds__(256) void k_wsplit(
    const float* __restrict__ W, short8* __restrict__ Bh,
    short8* __restrict__ Bl) {
  int t = blockIdx.x * 256 + threadIdx.x;  // 2048 threads total
  if (t >= 8 * 4 * 64) return;
  int lane = t & 63;
  int ct = (t >> 6) & 3;
  int ks = t >> 8;
  int k0 = ks * 32 + (lane >> 4) * 8;
  int col = ct * 16 + (lane & 15);
  short8 h8, l8;
#pragma unroll
  for (int j = 0; j < 8; ++j) {
    ushort hi, lo;
    split2(W[(size_t)(k0 + j) * D_OUT + col], hi, lo);
    h8[j] = (short)hi;
    l8[j] = (short)lo;
  }
  Bh[t] = h8;
  Bl[t] = l8;
}

// ---------------- Kernel 1: h = X*W + b via bf16 MFMA (hi/lo split) --------
__global__ __launch_bounds__(256) void k_gemm_mfma(
    const float* __restrict__ feat, const short8* __restrict__ Bh,
    const short8* __restrict__ Bl, const float* __restrict__ bias,
    const float* __restrict__ a1w, const float* __restrict__ a1b,
    const float* __restrict__ a2w, const float* __restrict__ a2b,
    float* __restrict__ h, float* __restrict__ a1, float* __restrict__ a2) {
  int wid = (blockIdx.x * 256 + threadIdx.x) >> 6;
  int lane = threadIdx.x & 63;
  if (wid >= N_NODES / 16) return;  // 3125 waves exactly
  int row0 = wid * 16;

  int arow = row0 + (lane & 15);
  const float* fp = feat + (size_t)arow * D_IN + ((lane >> 4) * 8);

  f32x4 acc[4];
#pragma unroll
  for (int ct = 0; ct < 4; ++ct) acc[ct] = (f32x4){0.f, 0.f, 0.f, 0.f};

#pragma unroll
  for (int ks = 0; ks < 8; ++ks) {
    float4 v0 = *reinterpret_cast<const float4*>(fp + ks * 32);
    float4 v1 = *reinterpret_cast<const float4*>(fp + ks * 32 + 4);
    float av[8] = {v0.x, v0.y, v0.z, v0.w, v1.x, v1.y, v1.z, v1.w};
    short8 ah, al;
#pragma unroll
    for (int j = 0; j < 8; ++j) {
      ushort hi, lo;
      split2(av[j], hi, lo);
      ah[j] = (short)hi;
      al[j] = (short)lo;
    }
#pragma unroll
    for (int ct = 0; ct < 4; ++ct) {
      short8 bh = Bh[(ks * 4 + ct) * 64 + lane];
      short8 bl = Bl[(ks * 4 + ct) * 64 + lane];
      acc[ct] = __builtin_amdgcn_mfma_f32_16x16x32_bf16(ah, bh, acc[ct], 0, 0, 0);
      acc[ct] = __builtin_amdgcn_mfma_f32_16x16x32_bf16(ah, bl, acc[ct], 0, 0, 0);
      acc[ct] = __builtin_amdgcn_mfma_f32_16x16x32_bf16(al, bh, acc[ct], 0, 0, 0);
    }
  }

  // Epilogue. C layout: col = lane&15 (within ct*16..), row = (lane>>4)*4 + r.
  int lo16 = lane & 15;
  int hi4 = (lane >> 4) * 4;
  float bv[4], w1[4], w2[4];
#pragma unroll
  for (int ct = 0; ct < 4; ++ct) {
    bv[ct] = bias[ct * 16 + lo16];
    w1[ct] = a1w[ct * 16 + lo16];
    w2[ct] = a2w[ct * 16 + lo16];
  }
  float b1 = a1b[0], b2 = a2b[0];

#pragma unroll
  for (int r = 0; r < 4; ++r) {
    int row = row0 + hi4 + r;
    float s1 = 0.f, s2 = 0.f;
#pragma unroll
    for (int ct = 0; ct < 4; ++ct) {
      float hv = acc[ct][r] + bv[ct];
      h[(size_t)row * D_OUT + ct * 16 + lo16] = hv;
      s1 = fmaf(hv, w1[ct], s1);
      s2 = fmaf(hv, w2[ct], s2);
    }
#pragma unroll
    for (int off = 1; off < 16; off <<= 1) {
      s1 += __shfl_xor(s1, off);
      s2 += __shfl_xor(s2, off);
    }
    if (lo16 == 0) {
      a1[row] = s1 + b1;
      a2[row] = s2 + b2;
    }
  }
}

// ---------------- Kernel 2: per-row edge histogram ----------
__global__ __launch_bounds__(256) void k_count(
    const int* __restrict__ rows, unsigned* __restrict__ counts) {
  int e = blockIdx.x * blockDim.x + threadIdx.x;
  if (e >= N_EDGES) return;
  atomicAdd(&counts[rows[e]], 1u);
}

// ---------------- Scan: counts -> exclusive prefix (start[]) ----------
__global__ __launch_bounds__(256) void k_scan_blocks(
    const unsigned* __restrict__ counts, unsigned* __restrict__ partial,
    unsigned* __restrict__ bsum) {
  int i = blockIdx.x * 256 + threadIdx.x;
  int lane = threadIdx.x & 63, wid = threadIdx.x >> 6;
  unsigned v = (i < N_NODES) ? counts[i] : 0u;
  unsigned x = v;
#pragma unroll
  for (int off = 1; off < 64; off <<= 1) {
    unsigned y = __shfl_up(x, off);
    if (lane >= off) x += y;
  }
  __shared__ unsigned wtot[4];
  if (lane == 63) wtot[wid] = x;
  __syncthreads();
  unsigned wo = 0;
  for (int wq = 0; wq < wid; ++wq) wo += wtot[wq];
  unsigned incl = x + wo;
  if (i < N_NODES) partial[i] = incl - v;
  if (threadIdx.x == 255) bsum[blockIdx.x] = incl;
}

__global__ __launch_bounds__(256) void k_scan_bsums(
    unsigned* __restrict__ bsum, int nblocks) {
  int i = threadIdx.x;
  int lane = i & 63, wid = i >> 6;
  unsigned v = (i < nblocks) ? bsum[i] : 0u;
  unsigned x = v;
#pragma unroll
  for (int off = 1; off < 64; off <<= 1) {
    unsigned y = __shfl_up(x, off);
    if (lane >= off) x += y;
  }
  __shared__ unsigned wtot[4];
  if (lane == 63) wtot[wid] = x;
  __syncthreads();
  unsigned wo = 0;
  for (int wq = 0; wq < wid; ++wq) wo += wtot[wq];
  if (i < nblocks) bsum[i] = (x + wo) - v;
}

__global__ __launch_bounds__(256) void k_scan_add(
    unsigned* __restrict__ start, const unsigned* __restrict__ bsum,
    unsigned* __restrict__ cursor) {
  int i = blockIdx.x * 256 + threadIdx.x;
  if (i < N_NODES) {
    unsigned s = start[i] + bsum[i >> 8];
    start[i] = s;
    cursor[i] = s;
  } else if (i == N_NODES) {
    start[N_NODES] = N_EDGES;
  }
}

// ---------------- Kernel 3: scatter edges into CSR order ----------
__global__ __launch_bounds__(256) void k_scatter(
    const int* __restrict__ rows, const int* __restrict__ cols,
    const float* __restrict__ a1, const float* __restrict__ a2,
    unsigned* __restrict__ cursor, int2* __restrict__ es) {
  int e = blockIdx.x * blockDim.x + threadIdx.x;
  if (e >= N_EDGES) return;
  int r = rows[e], c = cols[e];
  float s = a1[r] + a2[c];
  s = (s > 0.f) ? s : NEG_SLOPE * s;
  unsigned pos = atomicAdd(&cursor[r], 1u);
  es[pos] = make_int2(c, __float_as_int(s));
}

// ---------------- Kernel 3.5: in-place row softmax on es[].y --------------
// One 16-lane group per row; scores -> normalized attention weights.
__global__ __launch_bounds__(256) void k_softmax(
    const unsigned* __restrict__ start, int2* __restrict__ es) {
  int gt = blockIdx.x * blockDim.x + threadIdx.x;
  int r = gt >> 4;
  int sl = gt & 15;
  if (r >= N_NODES) return;
  int beg = (int)start[r], end = (int)start[r + 1];

  float m = -1e30f;
  for (int i = beg + sl; i < end; i += 16)
    m = fmaxf(m, __int_as_float(es[i].y));
#pragma unroll
  for (int off = 1; off < 16; off <<= 1) m = fmaxf(m, __shfl_xor(m, off, 16));

  float d = 0.f;
  for (int i = beg + sl; i < end; i += 16)
    d += __expf(__int_as_float(es[i].y) - m);
#pragma unroll
  for (int off = 1; off < 16; off <<= 1) d += __shfl_xor(d, off, 16);

  float inv = 1.0f / d;
  for (int i = beg + sl; i < end; i += 16) {
    float att = __expf(__int_as_float(es[i].y) - m) * inv;
    es[i].y = __float_as_int(att);
  }
}

// ---------------- Kernel 4: single-pass aggregate, 4-deep ILP --------------
// One wave per row, lane = output dim; es[].y already holds att.
__global__ __launch_bounds__(256) void k_row_agg(
    const unsigned* __restrict__ start, const int2* __restrict__ es,
    const float* __restrict__ h, float* __restrict__ out) {
  int gt = blockIdx.x * blockDim.x + threadIdx.x;
  int r = gt >> 6;
  int lane = gt & 63;
  if (r >= N_NODES) return;
  int beg = (int)start[r], end = (int)start[r + 1];

  float acc0 = 0.f, acc1 = 0.f, acc2 = 0.f, acc3 = 0.f;
  int i = beg;
  for (; i + 4 <= end; i += 4) {
    int4 e01 = *reinterpret_cast<const int4*>(&es[i]);
    int4 e23 = *reinterpret_cast<const int4*>(&es[i + 2]);
    acc0 = fmaf(__int_as_float(e01.y), h[(size_t)e01.x * D_OUT + lane], acc0);
    acc1 = fmaf(__int_as_float(e01.w), h[(size_t)e01.z * D_OUT + lane], acc1);
    acc2 = fmaf(__int_as_float(e23.y), h[(size_t)e23.x * D_OUT + lane], acc2);
    acc3 = fmaf(__int_as_float(e23.w), h[(size_t)e23.z * D_OUT + lane], acc3);
  }
  for (; i < end; ++i) {
    int2 e = es[i];
    acc0 = fmaf(__int_as_float(e.y), h[(size_t)e.x * D_OUT + lane], acc0);
  }
  out[(size_t)r * D_OUT + lane] = (acc0 + acc1) + (acc2 + acc3);
}

extern "C" void kernel_launch(void* const* d_in, const int* in_sizes, int n_in,
                              void* d_out, int out_size, void* d_ws, size_t ws_size,
                              hipStream_t stream) {
  const float* feat = (const float*)d_in[0];
  const int* eidx   = (const int*)d_in[1];   // [2, E] int32 (JAX x64 disabled)
  const float* W    = (const float*)d_in[3];
  const float* bias = (const float*)d_in[4];
  const float* a1w  = (const float*)d_in[5];
  const float* a1b  = (const float*)d_in[6];
  const float* a2w  = (const float*)d_in[7];
  const float* a2b  = (const float*)d_in[8];
  float* out = (float*)d_out;

  const int* rows = eidx;
  const int* cols = eidx + N_EDGES;

  // workspace layout (~20.4 MB)
  char* ws = (char*)d_ws;
  float*    h      = (float*)ws;                      // 12.8 MB
  int2*     es     = (int2*)(ws + 12800000);          // 6.4 MB
  float*    a1     = (float*)(ws + 19200000);         // 200 KB
  float*    a2     = (float*)(ws + 19400000);         // 200 KB
  unsigned* counts = (unsigned*)(ws + 19600000);      // 200 KB
  unsigned* start  = (unsigned*)(ws + 19800000);      // 200 KB (+4)
  unsigned* cursor = (unsigned*)(ws + 20000064);      // 200 KB
  unsigned* bsum   = (unsigned*)(ws + 20200064);      // 1 KB
  short8*   Bh     = (short8*)(ws + 20201088);        // 32 KB
  short8*   Bl     = (short8*)(ws + 20233856);        // 32 KB

  hipMemsetAsync(counts, 0, N_NODES * sizeof(unsigned), stream);

  const int SCAN_BLOCKS = (N_NODES + 255) / 256;  // 196

  k_wsplit<<<8, 256, 0, stream>>>(W, Bh, Bl);
  {
    int waves = N_NODES / 16;  // 3125
    int blocks = (waves + 3) / 4;
    k_gemm_mfma<<<blocks, 256, 0, stream>>>(feat, Bh, Bl, bias, a1w, a1b, a2w,
                                            a2b, h, a1, a2);
  }
  {
    int blocks = (N_EDGES + 255) / 256;
    k_count<<<blocks, 256, 0, stream>>>(rows, counts);
  }
  k_scan_blocks<<<SCAN_BLOCKS, 256, 0, stream>>>(counts, start, bsum);
  k_scan_bsums<<<1, 256, 0, stream>>>(bsum, SCAN_BLOCKS);
  k_scan_add<<<(N_NODES + 256) / 256, 256, 0, stream>>>(start, bsum, cursor);
  {
    int blocks = (N_EDGES + 255) / 256;
    k_scatter<<<blocks, 256, 0, stream>>>(rows, cols, a1, a2, cursor, es);
  }
  {
    long long threads = (long long)N_NODES * 16;
    int blocks = (int)((threads + 255) / 256);
    k_softmax<<<blocks, 256, 0, stream>>>(start, es);
  }
  {
    long long threads = (long long)N_NODES * 64;
    int blocks = (int)((threads + 255) / 256);
    k_row_agg<<<blocks, 256, 0, stream>>>(start, es, h, out);
  }
}